// Round 10
// baseline (32.170 us; speedup 1.0000x reference)
//
#include <hip/hip_runtime.h>
#include <math.h>

// Chamfer distance, B=8, N=M=4096, D=3, fp32.
// R10: single-sweep split-bf16 MFMA at proper occupancy.
// D[r][c] = sqA_r + sqB_c - 2 a_r.b_c  (rows=pcs1, cols=pcs2), K-packed:
//   slots 0-2 hiA*hiB | 3-5 hiA*loB | 6-8 loA*hiB | 9-11 loA*loB
//   slot 12,13 sqA_hi,lo * 1 | slot 14,15 1 * sqB_hi,lo
// Grid 512 = b(8) x rgroup(16) x cquarter(4); 512 thr, LB(512,4) ->
// 2 blocks/CU, 4 waves/SIMD. Wave w: r-tile rt=rgroup*8+w fixed (A in regs),
// sweeps 32 c-tiles. rowmin: lane-local rmin[16], ONE cross-lane reduce at
// end -> atomicMin(dist1u). colmin: 15-op tree + ds_atomicMin into block
// ldscol[1024]; block partials plain-stored, combined in red1.
// red1 folds the final scalar via last-block-done (counter zeroed in prep).
// MFMA floor: 131072 mfma * 64cyc / 1024 SIMD / 2.4GHz = 3.4 us.

typedef __attribute__((ext_vector_type(8)))  short bf16x8;
typedef __attribute__((ext_vector_type(16))) float f32x16;
typedef float f32x2 __attribute__((ext_vector_type(2)));

#define NPTS 4096
#define BATCH 8
#define FRAG_PER_B 8192u   // per batch: 128 tiles * 2 K-halves * 32 rows (uint4)

union FragCast { uint4 u; bf16x8 v; };

__device__ __forceinline__ unsigned short f2bf(float f) {
    unsigned u = __float_as_uint(f);
    return (unsigned short)((u + 0x7FFFu + ((u >> 16) & 1u)) >> 16);
}
__device__ __forceinline__ float bf2f(unsigned short h) {
    return __uint_as_float(((unsigned)h) << 16);
}
__device__ __forceinline__ unsigned pk(unsigned short a, unsigned short b) {
    return (unsigned)a | ((unsigned)b << 16);
}

// ---------------- prep: fa1, fb2, dist1u init, counter=0 ----------------
__global__ __launch_bounds__(256) void chamfer_prep(
    const float* __restrict__ pcs1, const float* __restrict__ pcs2,
    uint4* __restrict__ fa1, uint4* __restrict__ fb2,
    unsigned* __restrict__ dist1u, unsigned* __restrict__ counter)
{
    const int gid = blockIdx.x * 256 + threadIdx.x;  // [0, 32768)
    if (gid == 0) *counter = 0u;
    const int b   = gid >> 12;
    const int pt  = gid & 4095;

    dist1u[gid] = 0x7F800000u;   // +inf

    const int tile = pt >> 5, row = pt & 31;
    const size_t i0 = (size_t)b * FRAG_PER_B + ((size_t)tile * 2 + 0) * 32 + row;
    const size_t i1 = (size_t)b * FRAG_PER_B + ((size_t)tile * 2 + 1) * 32 + row;
    const unsigned short ONE = 0x3F80;

    // A-role from pcs1: hi/lo split of -2*coord + split of |a|^2
    {
        const float* s = pcs1 + ((size_t)b * NPTS + pt) * 3;
        float x = s[0], y = s[1], z = s[2];
        float sq = fmaf(x, x, fmaf(y, y, z * z));
        float m2x = -2.0f * x, m2y = -2.0f * y, m2z = -2.0f * z;
        unsigned short hx = f2bf(m2x), hy = f2bf(m2y), hz = f2bf(m2z);
        unsigned short lx = f2bf(m2x - bf2f(hx));
        unsigned short ly = f2bf(m2y - bf2f(hy));
        unsigned short lz = f2bf(m2z - bf2f(hz));
        unsigned short sh = f2bf(sq);
        unsigned short sl = f2bf(sq - bf2f(sh));
        fa1[i0] = make_uint4(pk(hx, hy), pk(hz, hx), pk(hy, hz), pk(lx, ly));
        fa1[i1] = make_uint4(pk(lz, lx), pk(ly, lz), pk(sh, sl), pk(ONE, ONE));
    }
    // B-role from pcs2: hi/lo split of raw coord + split of |b|^2
    {
        const float* s = pcs2 + ((size_t)b * NPTS + pt) * 3;
        float x = s[0], y = s[1], z = s[2];
        float sq = fmaf(x, x, fmaf(y, y, z * z));
        unsigned short px = f2bf(x), py = f2bf(y), pz = f2bf(z);
        unsigned short qx = f2bf(x - bf2f(px));
        unsigned short qy = f2bf(y - bf2f(py));
        unsigned short qz = f2bf(z - bf2f(pz));
        unsigned short sh = f2bf(sq);
        unsigned short sl = f2bf(sq - bf2f(sh));
        fb2[i0] = make_uint4(pk(px, py), pk(pz, qx), pk(qy, qz), pk(px, py));
        fb2[i1] = make_uint4(pk(pz, qx), pk(qy, qz), pk(ONE, ONE), pk(sh, sl));
    }
}

// ---------------- main: 512 blocks x 512 threads ----------------
__global__ __launch_bounds__(512, 4) void chamfer_mfma(
    const uint4* __restrict__ fa1, const uint4* __restrict__ fb2,
    unsigned* __restrict__ dist1u, unsigned* __restrict__ cpart)
{
    __shared__ unsigned ldscol[1024];   // colmin for this c-quarter

    const int bid    = blockIdx.x;
    const int b      = bid >> 6;           // 8
    const int rgroup = (bid >> 2) & 15;    // 16
    const int cq     = bid & 3;            // 4

    const int tid = threadIdx.x;
    const int w   = tid >> 6;
    const int l   = tid & 63;
    const int hf  = l >> 5;
    const int ln  = l & 31;
    const int rt  = rgroup * 8 + w;        // r-tile in [0,128)

    ((uint2*)ldscol)[tid] = make_uint2(0x7F800000u, 0x7F800000u);

    // fixed A-frag: this wave's 32 rows of cloud1
    FragCast aq;
    aq.u = fa1[(size_t)b * FRAG_PER_B + ((size_t)rt * 2 + hf) * 32 + ln];

    // B stream: c-tile ct (local) -> fb2[(cq*32+ct)*64 + hf*32 + ln]
    const uint4* bptr = fb2 + (size_t)b * FRAG_PER_B
                        + (size_t)cq * 2048 + hf * 32 + ln;

    const f32x16 cz = {0.f,0.f,0.f,0.f,0.f,0.f,0.f,0.f,
                       0.f,0.f,0.f,0.f,0.f,0.f,0.f,0.f};
    float rmin[16];
#pragma unroll
    for (int i = 0; i < 16; ++i) rmin[i] = 3.4e38f;

    __syncthreads();   // ldscol ready

    // depth-2 prefetch; final overreads (~2KB past fb2) land in dist1u
    // region of d_ws -- mapped, values unused.
    uint4 p0 = bptr[0];
    uint4 p1 = bptr[64];
#pragma unroll 2
    for (int ct = 0; ct < 32; ++ct) {
        FragCast bq; bq.u = p0;
        p0 = p1;
        p1 = bptr[(size_t)(ct + 2) * 64];
        f32x16 D = __builtin_amdgcn_mfma_f32_32x32x16_bf16(aq.v, bq.v, cz, 0, 0, 0);

        // rowmin accumulate (16 independent v_min)
#pragma unroll
        for (int i = 0; i < 16; ++i) rmin[i] = fminf(rmin[i], D[i]);

        // colmin: 15-op tree, clamp, ds atomic (lanes hf0/hf1 pair per addr)
        float a0 = fminf(D[0],  D[1]);
        float a1 = fminf(D[2],  D[3]);
        float a2 = fminf(D[4],  D[5]);
        float a3 = fminf(D[6],  D[7]);
        float a4 = fminf(D[8],  D[9]);
        float a5 = fminf(D[10], D[11]);
        float a6 = fminf(D[12], D[13]);
        float a7 = fminf(D[14], D[15]);
        float b0 = fminf(a0, a1), b1 = fminf(a2, a3);
        float b2 = fminf(a4, a5), b3 = fminf(a6, a7);
        float cm = fminf(fminf(b0, b1), fminf(b2, b3));
        cm = fmaxf(cm, 0.0f);
        atomicMin(&ldscol[ct * 32 + ln], __float_as_uint(cm));
    }

    // ---- rowmin epilogue: one cross-lane reduce per sweep ----
#pragma unroll
    for (int off = 1; off < 32; off <<= 1) {
#pragma unroll
        for (int i = 0; i < 16; ++i)
            rmin[i] = fminf(rmin[i], __shfl_xor(rmin[i], off, 64));
    }
    float v = 3.4e38f;
#pragma unroll
    for (int reg = 0; reg < 16; ++reg)
        if (ln == reg) v = rmin[reg];      // static-select, stays in regs
    if (ln < 16) {
        const int row = (ln & 3) + 8 * (ln >> 2) + 4 * hf;
        atomicMin(&dist1u[(size_t)b * NPTS + rt * 32 + row],
                  __float_as_uint(fmaxf(v, 0.0f)));
    }

    // ---- colmin partial write-out (plain stores, deterministic) ----
    __syncthreads();
    if (tid < 256) {
        uint4 vv = ((const uint4*)ldscol)[tid];
        ((uint4*)&cpart[((size_t)(b * 4 + cq) * 16 + rgroup) * 1024])[tid] = vv;
    }
}

// ---------------- red1: combine + final scalar (last-block-done) ----------
__global__ __launch_bounds__(256) void chamfer_red1(
    const unsigned* __restrict__ dist1u, const unsigned* __restrict__ cpart,
    float* __restrict__ bpart, unsigned* __restrict__ counter,
    float* __restrict__ out)
{
    __shared__ float ws4[4];
    const int t  = threadIdx.x;
    const int tg = blockIdx.x * 256 + t;       // [0, 32768)
    const int b  = tg >> 12;
    const int c  = tg & 4095;
    const int cq = c >> 10, cl = c & 1023;

    unsigned m = 0xFFFFFFFFu;
    const unsigned* base = &cpart[((size_t)(b * 4 + cq) * 16) * 1024 + cl];
#pragma unroll
    for (int rg = 0; rg < 16; ++rg) {
        unsigned u = base[(size_t)rg * 1024];
        m = (u < m) ? u : m;
    }

    float s = sqrtf(__uint_as_float(m)) + sqrtf(__uint_as_float(dist1u[tg]));
#pragma unroll
    for (int off = 1; off < 64; off <<= 1) s += __shfl_xor(s, off, 64);
    if ((t & 63) == 0) ws4[t >> 6] = s;
    __syncthreads();
    if (t == 0) {
        bpart[blockIdx.x] = ws4[0] + ws4[1] + ws4[2] + ws4[3];
        __threadfence();
        unsigned old = atomicAdd(counter, 1u);
        if (old == 127u) {                  // last block: fixed-order sum
            __threadfence();
            float tot = 0.0f;
            for (int i = 0; i < 128; ++i) tot += bpart[i];
            out[0] = tot * (1.0f / 65536.0f);
            // loss = 0.5*(sum1/32768 + sum2/32768) = (sum1+sum2)/65536
        }
    }
}

// ---------------- fallback (proven R5 vector path, 4KB ws) ----------------
#define CPAIRS 1024
#define PA 16
#define RSTRIDE 68

__device__ __forceinline__ f32x2 pk_fma_lo(f32x2 c, f32x2 q, f32x2 acc) {
    f32x2 d;
    asm("v_pk_fma_f32 %0, %1, %2, %3 op_sel:[0,0,0] op_sel_hi:[0,1,1]"
        : "=v"(d) : "v"(c), "v"(q), "v"(acc));
    return d;
}
__device__ __forceinline__ f32x2 pk_fma_hi(f32x2 c, f32x2 q, f32x2 acc) {
    f32x2 d;
    asm("v_pk_fma_f32 %0, %1, %2, %3 op_sel:[1,0,0] op_sel_hi:[1,1,1]"
        : "=v"(d) : "v"(c), "v"(q), "v"(acc));
    return d;
}
__device__ __forceinline__ void vmin3(float& acc, float a, float b) {
    asm("v_min3_f32 %0, %1, %2, %3" : "=v"(acc) : "v"(acc), "v"(a), "v"(b));
}

__global__ __launch_bounds__(256, 4) void chamfer_vec(
    const float* __restrict__ pcs1, const float* __restrict__ pcs2,
    float* __restrict__ partials)
{
    __shared__ float4 lds[2 * CPAIRS];
    float4* bx = lds;
    float4* bz = lds + CPAIRS;

    const int bid = blockIdx.x;
    const int dir = bid >> 9;
    const int b   = (bid >> 6) & 7;
    const int ach = bid & 63;

    const float* A  = dir ? pcs2 : pcs1;
    const float* Bp = dir ? pcs1 : pcs2;
    const float* abase = A  + (size_t)b * NPTS * 3;
    const float* bbase = Bp + (size_t)b * NPTS * 3;

    const int tid = threadIdx.x;
    const int w   = tid >> 6;
    const int l   = tid & 63;

    const int apt = ach * 64 + w * PA;
    f32x2 cx[PA / 2], cy[PA / 2], cz2[PA / 2];
    float tmin[PA];
#pragma unroll
    for (int p2 = 0; p2 < PA / 2; ++p2) {
        const float* s = abase + (size_t)(apt + 2 * p2) * 3;
        cx[p2]  = (f32x2){-2.0f * s[0], -2.0f * s[3]};
        cy[p2]  = (f32x2){-2.0f * s[1], -2.0f * s[4]};
        cz2[p2] = (f32x2){-2.0f * s[2], -2.0f * s[5]};
        tmin[2 * p2] = 3.4e38f; tmin[2 * p2 + 1] = 3.4e38f;
    }

    for (int c = 0; c < 2; ++c) {
        if (c) __syncthreads();
#pragma unroll
        for (int i = 0; i < CPAIRS / 256; ++i) {
            int j  = i * 256 + tid;
            const float* s = bbase + (size_t)(c * CPAIRS + j) * 6;
            float x0 = s[0], y0 = s[1], z0 = s[2];
            float x1 = s[3], y1 = s[4], z1 = s[5];
            bx[j] = make_float4(x0, x1, y0, y1);
            bz[j] = make_float4(z0, z1,
                                fmaf(x0, x0, fmaf(y0, y0, z0 * z0)),
                                fmaf(x1, x1, fmaf(y1, y1, z1 * z1)));
        }
        __syncthreads();
#pragma unroll 4
        for (int t = 0; t < CPAIRS / 64; ++t) {
            float4 X = bx[t * 64 + l];
            float4 Z = bz[t * 64 + l];
            f32x2 qx = (f32x2){X.x, X.y};
            f32x2 qy = (f32x2){X.z, X.w};
            f32x2 qz = (f32x2){Z.x, Z.y};
            f32x2 qw = (f32x2){Z.z, Z.w};
#pragma unroll
            for (int p2 = 0; p2 < PA / 2; ++p2) {
                f32x2 d0 = pk_fma_lo(cz2[p2], qz, qw);
                d0 = pk_fma_lo(cy[p2], qy, d0);
                d0 = pk_fma_lo(cx[p2], qx, d0);
                vmin3(tmin[2 * p2], d0.x, d0.y);
                f32x2 d1 = pk_fma_hi(cz2[p2], qz, qw);
                d1 = pk_fma_hi(cy[p2], qy, d1);
                d1 = pk_fma_hi(cx[p2], qx, d1);
                vmin3(tmin[2 * p2 + 1], d1.x, d1.y);
            }
        }
    }

    __syncthreads();
    float* lds2 = (float*)lds;
#pragma unroll
    for (int p = 0; p < PA; ++p)
        lds2[(w * PA + p) * RSTRIDE + l] = tmin[p];
    __syncthreads();

    if (tid < 64) {
        const int g = tid;
        float m = 3.4e38f;
        const float4* row = (const float4*)&lds2[g * RSTRIDE];
#pragma unroll
        for (int i = 0; i < 16; ++i) {
            float4 v = row[i];
            m = fminf(fminf(m, fminf(v.x, v.y)), fminf(v.z, v.w));
        }
        const int ap = ach * 64 + g;
        float x = abase[ap * 3 + 0], y = abase[ap * 3 + 1], z = abase[ap * 3 + 2];
        float s = sqrtf(fmaxf(fmaf(x, x, fmaf(y, y, z * z)) + m, 0.0f));
#pragma unroll
        for (int off = 1; off < 64; off <<= 1) s += __shfl_xor(s, off, 64);
        if (g == 0) partials[bid] = s;
    }
}

__global__ __launch_bounds__(256) void chamfer_final(
    const float* __restrict__ partials, int n, float scale,
    float* __restrict__ out)
{
    __shared__ float ws4[4];
    const int t = threadIdx.x;
    float v = 0.0f;
    for (int i = t; i < n; i += 256) v += partials[i];
#pragma unroll
    for (int off = 1; off < 64; off <<= 1) v += __shfl_xor(v, off, 64);
    if ((t & 63) == 0) ws4[t >> 6] = v;
    __syncthreads();
    if (t == 0)
        out[0] = (ws4[0] + ws4[1] + ws4[2] + ws4[3]) * scale;
}

extern "C" void kernel_launch(void* const* d_in, const int* in_sizes, int n_in,
                              void* d_out, int out_size, void* d_ws, size_t ws_size,
                              hipStream_t stream) {
    const float* pcs1 = (const float*)d_in[0];
    const float* pcs2 = (const float*)d_in[1];
    float* out = (float*)d_out;

    const size_t MB = 1048576;
    // fa1 1MB | fb2 1MB | dist1u 128KB | cpart 2MB | bpart 512B | counter
    const size_t need = 4 * MB + 128 * 1024 + 4096;

    if (ws_size >= need) {
        char* w = (char*)d_ws;
        uint4*    fa1     = (uint4*)(w);
        uint4*    fb2     = (uint4*)(w + 1 * MB);
        unsigned* dist1u  = (unsigned*)(w + 2 * MB);
        unsigned* cpart   = (unsigned*)(w + 2 * MB + 128 * 1024);
        float*    bpart   = (float*)(w + 4 * MB + 128 * 1024);
        unsigned* counter = (unsigned*)(w + 4 * MB + 128 * 1024 + 512);

        chamfer_prep<<<dim3(128), dim3(256), 0, stream>>>(
            pcs1, pcs2, fa1, fb2, dist1u, counter);
        chamfer_mfma<<<dim3(512), dim3(512), 0, stream>>>(
            fa1, fb2, dist1u, cpart);
        chamfer_red1<<<dim3(128), dim3(256), 0, stream>>>(
            dist1u, cpart, bpart, counter, out);
    } else {
        float* partials = (float*)d_ws;
        chamfer_vec  <<<dim3(1024), dim3(256), 0, stream>>>(pcs1, pcs2, partials);
        chamfer_final<<<dim3(1),    dim3(256), 0, stream>>>(
            partials, 1024, 1.0f / 65536.0f, out);
    }
}

// Round 11
// 24.910 us; speedup vs baseline: 1.2915x; 1.2915x over previous
//
#include <hip/hip_runtime.h>
#include <math.h>

// Chamfer distance, B=8, N=M=4096, D=3, fp32.
// R11: R8's proven two-sweep split-bf16 MFMA structure (23.0us best), with
// the fixed costs removed:
//   - prep kernel eliminated: fragments built on the fly (B-frags per lane
//     in regs; A-frags computed during LDS staging from raw pcs)
//   - red2 eliminated: last-block-done counter in red1 (R10-verified)
//   - main: wave holds TWO B-frags -> 2 independent MFMAs per A ds_read;
//     one staging phase (32KB LDS), 2 barriers/block total
// K-packing (verified absmax=0 since R7/R8):
//   slots 0-2 hiA*hiB | 3-5 hiA*loB | 6-8 loA*hiB | 9-11 loA*loB
//   slot 12,13 sqA_hi,lo * 1 | slot 14,15 1 * sqB_hi,lo
//   => D[r][c] = sqA_r + sqB_c - 2 a_r.b_c   (fp32 accum)
// C/D layout: col = lane&31, rows spread over 16 regs + lane>>5 (m74/m101).
// colmin per tile = in-register tree; min over sweep in acc; one shfl at end.
// MFMA floor: 262144 mfma / 1024 SIMD * 32 cyc / 2.4GHz = 3.4 us.

typedef __attribute__((ext_vector_type(8)))  short bf16x8;
typedef __attribute__((ext_vector_type(16))) float f32x16;
typedef float f32x2 __attribute__((ext_vector_type(2)));

#define NPTS 4096
#define BATCH 8

union FragCast { uint4 u; bf16x8 v; };

__device__ __forceinline__ unsigned short f2bf(float f) {
    unsigned u = __float_as_uint(f);
    return (unsigned short)((u + 0x7FFFu + ((u >> 16) & 1u)) >> 16);
}
__device__ __forceinline__ float bf2f(unsigned short h) {
    return __uint_as_float(((unsigned)h) << 16);
}
__device__ __forceinline__ unsigned pk(unsigned short a, unsigned short b) {
    return (unsigned)a | ((unsigned)b << 16);
}

// A-role frag pair (K-halves) for one point: hi/lo split of -2*coord + |a|^2
__device__ __forceinline__ void build_afrag(float x, float y, float z,
                                            uint4& a0, uint4& a1) {
    float sq  = fmaf(x, x, fmaf(y, y, z * z));
    float m2x = -2.0f * x, m2y = -2.0f * y, m2z = -2.0f * z;
    unsigned short hx = f2bf(m2x), hy = f2bf(m2y), hz = f2bf(m2z);
    unsigned short lx = f2bf(m2x - bf2f(hx));
    unsigned short ly = f2bf(m2y - bf2f(hy));
    unsigned short lz = f2bf(m2z - bf2f(hz));
    unsigned short sh = f2bf(sq);
    unsigned short sl = f2bf(sq - bf2f(sh));
    const unsigned short ONE = 0x3F80;
    a0 = make_uint4(pk(hx, hy), pk(hz, hx), pk(hy, hz), pk(lx, ly));
    a1 = make_uint4(pk(lz, lx), pk(ly, lz), pk(sh, sl), pk(ONE, ONE));
}

// B-role frag (one K-half, selected by hf) for one point
__device__ __forceinline__ uint4 build_bfrag(float x, float y, float z, int hf) {
    float sq = fmaf(x, x, fmaf(y, y, z * z));
    unsigned short px = f2bf(x), py = f2bf(y), pz = f2bf(z);
    unsigned short qx = f2bf(x - bf2f(px));
    unsigned short qy = f2bf(y - bf2f(py));
    unsigned short qz = f2bf(z - bf2f(pz));
    unsigned short sh = f2bf(sq);
    unsigned short sl = f2bf(sq - bf2f(sh));
    const unsigned short ONE = 0x3F80;
    return hf == 0
        ? make_uint4(pk(px, py), pk(pz, qx), pk(qy, qz), pk(px, py))
        : make_uint4(pk(pz, qx), pk(qy, qz), pk(ONE, ONE), pk(sh, sl));
}

// ---------------- main: 1024 blocks x 256 threads (4 waves) ----------------
// bid = dir(2) x b(8) x rq(4) x mg(16). Wave w: m-tiles mt0=mg*8+w*2, mt0+1
// (B-frags in regs); sweeps 32 r-tiles of A-cloud quarter rq (staged in LDS).
__global__ __launch_bounds__(256, 4) void chamfer_fused(
    const float* __restrict__ pcs1, const float* __restrict__ pcs2,
    float* __restrict__ cpart, unsigned* __restrict__ counter)
{
    __shared__ uint4 afrag[2048];   // 32 tiles * 2 K-halves * 32 rows = 32 KB

    const int bid = blockIdx.x;
    const int dir = bid >> 9;
    const int b   = (bid >> 6) & 7;
    const int rq  = (bid >> 4) & 3;
    const int mg  = bid & 15;
    const int tid = threadIdx.x;

    if (bid == 0 && tid == 0) *counter = 0u;   // reset for red1 (each call)

    // dir 0: cols/outputs = pcs1 points, rows swept = pcs2; dir 1 swapped
    const float* bbase = (dir ? pcs2 : pcs1) + (size_t)b * NPTS * 3;
    const float* abase = (dir ? pcs1 : pcs2) + (size_t)b * NPTS * 3;

    const int w   = tid >> 6;
    const int l   = tid & 63;
    const int hf  = l >> 5;
    const int ln  = l & 31;
    const int mt0 = mg * 8 + w * 2;

    // ---- wave-fixed B-frags (2 m-tiles, built in registers) ----
    FragCast bq0, bq1;
    {
        const float* s0 = bbase + (size_t)(mt0 * 32 + ln) * 3;
        bq0.u = build_bfrag(s0[0], s0[1], s0[2], hf);
        const float* s1 = bbase + (size_t)((mt0 + 1) * 32 + ln) * 3;
        bq1.u = build_bfrag(s1[0], s1[1], s1[2], hf);
    }

    // ---- stage A-frags: quarter rq (1024 points), built on the fly ----
    {
        const float4* src = (const float4*)(abase + (size_t)rq * 3072);
        float4 f0 = src[3 * tid + 0];
        float4 f1 = src[3 * tid + 1];
        float4 f2 = src[3 * tid + 2];
        float xs[4] = {f0.x, f0.w, f1.z, f2.y};
        float ys[4] = {f0.y, f1.x, f1.w, f2.z};
        float zs[4] = {f0.z, f1.y, f2.x, f2.w};
        const int jt = tid >> 3;           // tile (8 threads/tile)
        const int r0 = (tid & 7) * 4;      // first row
#pragma unroll
        for (int i = 0; i < 4; ++i) {
            uint4 a0, a1;
            build_afrag(xs[i], ys[i], zs[i], a0, a1);
            afrag[jt * 64 + r0 + i]      = a0;   // K-half 0
            afrag[jt * 64 + 32 + r0 + i] = a1;   // K-half 1
        }
    }
    __syncthreads();

    const f32x16 cz = {0.f,0.f,0.f,0.f,0.f,0.f,0.f,0.f,
                       0.f,0.f,0.f,0.f,0.f,0.f,0.f,0.f};
    float acc0 = 3.4e38f, acc1 = 3.4e38f;

    // ---- hot loop: 32 iters x (1 ds_read_b128 + 2 indep MFMA + 2 min-trees)
#pragma unroll 2
    for (int j = 0; j < 32; ++j) {
        FragCast aq;
        aq.u = afrag[j * 64 + hf * 32 + ln];
        f32x16 D0 = __builtin_amdgcn_mfma_f32_32x32x16_bf16(aq.v, bq0.v, cz, 0, 0, 0);
        f32x16 D1 = __builtin_amdgcn_mfma_f32_32x32x16_bf16(aq.v, bq1.v, cz, 0, 0, 0);
        // 16 -> 1 min tree per D (fminf pairs fuse to v_min3)
        {
            float m0 = fminf(fminf(D0[0],  D0[1]),  D0[2]);
            float m1 = fminf(fminf(D0[3],  D0[4]),  D0[5]);
            float m2 = fminf(fminf(D0[6],  D0[7]),  D0[8]);
            float m3 = fminf(fminf(D0[9],  D0[10]), D0[11]);
            float m4 = fminf(fminf(D0[12], D0[13]), D0[14]);
            float n0 = fminf(fminf(m0, m1), m2);
            float n1 = fminf(fminf(m3, m4), D0[15]);
            acc0 = fminf(fminf(acc0, n0), n1);
        }
        {
            float m0 = fminf(fminf(D1[0],  D1[1]),  D1[2]);
            float m1 = fminf(fminf(D1[3],  D1[4]),  D1[5]);
            float m2 = fminf(fminf(D1[6],  D1[7]),  D1[8]);
            float m3 = fminf(fminf(D1[9],  D1[10]), D1[11]);
            float m4 = fminf(fminf(D1[12], D1[13]), D1[14]);
            float n0 = fminf(fminf(m0, m1), m2);
            float n1 = fminf(fminf(m3, m4), D1[15]);
            acc1 = fminf(fminf(acc1, n0), n1);
        }
    }

    // lanes l and l+32 hold complementary row halves of the same col
    acc0 = fminf(acc0, __shfl_xor(acc0, 32, 64));
    acc1 = fminf(acc1, __shfl_xor(acc1, 32, 64));

    const int   mt  = mt0 + hf;                 // hf0 lanes: mt0, hf1: mt0+1
    const float val = fmaxf(hf ? acc1 : acc0, 0.0f);   // clamp cancellation
    cpart[((((size_t)(dir * 8 + b) * 128 + mt) * 4 + rq) << 5) + ln] = val;
}

// ---------------- red1: 65536 col-mins -> scalar (last-block-done) --------
__global__ __launch_bounds__(256) void chamfer_red1(
    const float* __restrict__ cpart, float* __restrict__ bpart,
    unsigned* __restrict__ counter, float* __restrict__ out)
{
    __shared__ float ws4[4];
    const int t  = threadIdx.x;
    const int tg = blockIdx.x * 256 + t;        // [0, 65536): (dir,b,mt,ln)
    const float* p = cpart + ((size_t)(tg >> 5) << 7) + (tg & 31);
    float m = fminf(fminf(p[0], p[32]), fminf(p[64], p[96]));  // min over rq
    float s = sqrtf(m);                          // clamped in main
#pragma unroll
    for (int off = 1; off < 64; off <<= 1) s += __shfl_xor(s, off, 64);
    if ((t & 63) == 0) ws4[t >> 6] = s;
    __syncthreads();
    if (t == 0) {
        bpart[blockIdx.x] = ws4[0] + ws4[1] + ws4[2] + ws4[3];
        __threadfence();
        unsigned old = atomicAdd(counter, 1u);
        if (old == 255u) {                       // last block: fixed-order sum
            __threadfence();
            float tot = 0.0f;
            for (int i = 0; i < 256; ++i) tot += bpart[i];
            out[0] = tot * (1.0f / 65536.0f);
            // loss = 0.5*(sum1/32768 + sum2/32768) = (sum1+sum2)/65536
        }
    }
}

// ---------------- fallback (proven R5 vector path, 4KB ws) ----------------
#define CPAIRS 1024
#define PA 16
#define RSTRIDE 68

__device__ __forceinline__ f32x2 pk_fma_lo(f32x2 c, f32x2 q, f32x2 acc) {
    f32x2 d;
    asm("v_pk_fma_f32 %0, %1, %2, %3 op_sel:[0,0,0] op_sel_hi:[0,1,1]"
        : "=v"(d) : "v"(c), "v"(q), "v"(acc));
    return d;
}
__device__ __forceinline__ f32x2 pk_fma_hi(f32x2 c, f32x2 q, f32x2 acc) {
    f32x2 d;
    asm("v_pk_fma_f32 %0, %1, %2, %3 op_sel:[1,0,0] op_sel_hi:[1,1,1]"
        : "=v"(d) : "v"(c), "v"(q), "v"(acc));
    return d;
}
__device__ __forceinline__ void vmin3(float& acc, float a, float b) {
    asm("v_min3_f32 %0, %1, %2, %3" : "=v"(acc) : "v"(acc), "v"(a), "v"(b));
}

__global__ __launch_bounds__(256, 4) void chamfer_vec(
    const float* __restrict__ pcs1, const float* __restrict__ pcs2,
    float* __restrict__ partials)
{
    __shared__ float4 lds[2 * CPAIRS];
    float4* bx = lds;
    float4* bz = lds + CPAIRS;

    const int bid = blockIdx.x;
    const int dir = bid >> 9;
    const int b   = (bid >> 6) & 7;
    const int ach = bid & 63;

    const float* A  = dir ? pcs2 : pcs1;
    const float* Bp = dir ? pcs1 : pcs2;
    const float* abase = A  + (size_t)b * NPTS * 3;
    const float* bbase = Bp + (size_t)b * NPTS * 3;

    const int tid = threadIdx.x;
    const int w   = tid >> 6;
    const int l   = tid & 63;

    const int apt = ach * 64 + w * PA;
    f32x2 cx[PA / 2], cy[PA / 2], cz2[PA / 2];
    float tmin[PA];
#pragma unroll
    for (int p2 = 0; p2 < PA / 2; ++p2) {
        const float* s = abase + (size_t)(apt + 2 * p2) * 3;
        cx[p2]  = (f32x2){-2.0f * s[0], -2.0f * s[3]};
        cy[p2]  = (f32x2){-2.0f * s[1], -2.0f * s[4]};
        cz2[p2] = (f32x2){-2.0f * s[2], -2.0f * s[5]};
        tmin[2 * p2] = 3.4e38f; tmin[2 * p2 + 1] = 3.4e38f;
    }

    for (int c = 0; c < 2; ++c) {
        if (c) __syncthreads();
#pragma unroll
        for (int i = 0; i < CPAIRS / 256; ++i) {
            int j  = i * 256 + tid;
            const float* s = bbase + (size_t)(c * CPAIRS + j) * 6;
            float x0 = s[0], y0 = s[1], z0 = s[2];
            float x1 = s[3], y1 = s[4], z1 = s[5];
            bx[j] = make_float4(x0, x1, y0, y1);
            bz[j] = make_float4(z0, z1,
                                fmaf(x0, x0, fmaf(y0, y0, z0 * z0)),
                                fmaf(x1, x1, fmaf(y1, y1, z1 * z1)));
        }
        __syncthreads();
#pragma unroll 4
        for (int t = 0; t < CPAIRS / 64; ++t) {
            float4 X = bx[t * 64 + l];
            float4 Z = bz[t * 64 + l];
            f32x2 qx = (f32x2){X.x, X.y};
            f32x2 qy = (f32x2){X.z, X.w};
            f32x2 qz = (f32x2){Z.x, Z.y};
            f32x2 qw = (f32x2){Z.z, Z.w};
#pragma unroll
            for (int p2 = 0; p2 < PA / 2; ++p2) {
                f32x2 d0 = pk_fma_lo(cz2[p2], qz, qw);
                d0 = pk_fma_lo(cy[p2], qy, d0);
                d0 = pk_fma_lo(cx[p2], qx, d0);
                vmin3(tmin[2 * p2], d0.x, d0.y);
                f32x2 d1 = pk_fma_hi(cz2[p2], qz, qw);
                d1 = pk_fma_hi(cy[p2], qy, d1);
                d1 = pk_fma_hi(cx[p2], qx, d1);
                vmin3(tmin[2 * p2 + 1], d1.x, d1.y);
            }
        }
    }

    __syncthreads();
    float* lds2 = (float*)lds;
#pragma unroll
    for (int p = 0; p < PA; ++p)
        lds2[(w * PA + p) * RSTRIDE + l] = tmin[p];
    __syncthreads();

    if (tid < 64) {
        const int g = tid;
        float m = 3.4e38f;
        const float4* row = (const float4*)&lds2[g * RSTRIDE];
#pragma unroll
        for (int i = 0; i < 16; ++i) {
            float4 v = row[i];
            m = fminf(fminf(m, fminf(v.x, v.y)), fminf(v.z, v.w));
        }
        const int ap = ach * 64 + g;
        float x = abase[ap * 3 + 0], y = abase[ap * 3 + 1], z = abase[ap * 3 + 2];
        float s = sqrtf(fmaxf(fmaf(x, x, fmaf(y, y, z * z)) + m, 0.0f));
#pragma unroll
        for (int off = 1; off < 64; off <<= 1) s += __shfl_xor(s, off, 64);
        if (g == 0) partials[bid] = s;
    }
}

__global__ __launch_bounds__(256) void chamfer_final(
    const float* __restrict__ partials, int n, float scale,
    float* __restrict__ out)
{
    __shared__ float ws4[4];
    const int t = threadIdx.x;
    float v = 0.0f;
    for (int i = t; i < n; i += 256) v += partials[i];
#pragma unroll
    for (int off = 1; off < 64; off <<= 1) v += __shfl_xor(v, off, 64);
    if ((t & 63) == 0) ws4[t >> 6] = v;
    __syncthreads();
    if (t == 0)
        out[0] = (ws4[0] + ws4[1] + ws4[2] + ws4[3]) * scale;
}

extern "C" void kernel_launch(void* const* d_in, const int* in_sizes, int n_in,
                              void* d_out, int out_size, void* d_ws, size_t ws_size,
                              hipStream_t stream) {
    const float* pcs1 = (const float*)d_in[0];
    const float* pcs2 = (const float*)d_in[1];
    float* out = (float*)d_out;

    const size_t MB = 1048576;
    // cpart 1MB | bpart 1KB | counter
    const size_t need = MB + 4096;

    if (ws_size >= need) {
        char* w = (char*)d_ws;
        float*    cpart   = (float*)(w);
        float*    bpart   = (float*)(w + MB);
        unsigned* counter = (unsigned*)(w + MB + 1024);

        chamfer_fused<<<dim3(1024), dim3(256), 0, stream>>>(
            pcs1, pcs2, cpart, counter);
        chamfer_red1 <<<dim3(256),  dim3(256), 0, stream>>>(
            cpart, bpart, counter, out);
    } else {
        float* partials = (float*)d_ws;
        chamfer_vec  <<<dim3(1024), dim3(256), 0, stream>>>(pcs1, pcs2, partials);
        chamfer_final<<<dim3(1),    dim3(256), 0, stream>>>(
            partials, 1024, 1.0f / 65536.0f, out);
    }
}

// Round 12
// 23.329 us; speedup vs baseline: 1.3789x; 1.0677x over previous
//
#include <hip/hip_runtime.h>
#include <math.h>

// Chamfer distance, B=8, N=M=4096, D=3, fp32.
// R12 = R11's fused two-sweep split-bf16 MFMA with two surgical fixes:
//  (1) hot loop: per-tile 15-op dependent min-TREE replaced by 16 INDEPENDENT
//      v_min into persistent acc regs (tree hoisted to epilogue). Breaks the
//      dependence chain that was defeating MFMA/VALU overlap; shrinks live
//      ranges (no 2x f32x16 + tree temps under unroll-2).
//  (2) red1 last-block: serial 256-iter sum -> block-parallel reduce
//      (deterministic fixed-shape tree).
// K-packing (verified absmax=0 since R7):
//   slots 0-2 hiA*hiB | 3-5 hiA*loB | 6-8 loA*hiB | 9-11 loA*loB
//   slot 12,13 sqA_hi,lo * 1 | slot 14,15 1 * sqB_hi,lo
//   => D[r][c] = sqA_r + sqB_c - 2 a_r.b_c  (fp32 accum)
// MFMA floor: 262144 mfma / 1024 SIMD * 32 cyc / 2.4GHz = 3.4 us;
// VALU floor identical (1 v_min per pair) -> both pipes co-bound.

typedef __attribute__((ext_vector_type(8)))  short bf16x8;
typedef __attribute__((ext_vector_type(16))) float f32x16;
typedef float f32x2 __attribute__((ext_vector_type(2)));

#define NPTS 4096
#define BATCH 8

union FragCast { uint4 u; bf16x8 v; };

__device__ __forceinline__ unsigned short f2bf(float f) {
    unsigned u = __float_as_uint(f);
    return (unsigned short)((u + 0x7FFFu + ((u >> 16) & 1u)) >> 16);
}
__device__ __forceinline__ float bf2f(unsigned short h) {
    return __uint_as_float(((unsigned)h) << 16);
}
__device__ __forceinline__ unsigned pk(unsigned short a, unsigned short b) {
    return (unsigned)a | ((unsigned)b << 16);
}

__device__ __forceinline__ void build_afrag(float x, float y, float z,
                                            uint4& a0, uint4& a1) {
    float sq  = fmaf(x, x, fmaf(y, y, z * z));
    float m2x = -2.0f * x, m2y = -2.0f * y, m2z = -2.0f * z;
    unsigned short hx = f2bf(m2x), hy = f2bf(m2y), hz = f2bf(m2z);
    unsigned short lx = f2bf(m2x - bf2f(hx));
    unsigned short ly = f2bf(m2y - bf2f(hy));
    unsigned short lz = f2bf(m2z - bf2f(hz));
    unsigned short sh = f2bf(sq);
    unsigned short sl = f2bf(sq - bf2f(sh));
    const unsigned short ONE = 0x3F80;
    a0 = make_uint4(pk(hx, hy), pk(hz, hx), pk(hy, hz), pk(lx, ly));
    a1 = make_uint4(pk(lz, lx), pk(ly, lz), pk(sh, sl), pk(ONE, ONE));
}

__device__ __forceinline__ uint4 build_bfrag(float x, float y, float z, int hf) {
    float sq = fmaf(x, x, fmaf(y, y, z * z));
    unsigned short px = f2bf(x), py = f2bf(y), pz = f2bf(z);
    unsigned short qx = f2bf(x - bf2f(px));
    unsigned short qy = f2bf(y - bf2f(py));
    unsigned short qz = f2bf(z - bf2f(pz));
    unsigned short sh = f2bf(sq);
    unsigned short sl = f2bf(sq - bf2f(sh));
    const unsigned short ONE = 0x3F80;
    return hf == 0
        ? make_uint4(pk(px, py), pk(pz, qx), pk(qy, qz), pk(px, py))
        : make_uint4(pk(pz, qx), pk(qy, qz), pk(ONE, ONE), pk(sh, sl));
}

// ---------------- main: 1024 blocks x 256 threads (4 waves) ----------------
__global__ __launch_bounds__(256, 4) void chamfer_fused(
    const float* __restrict__ pcs1, const float* __restrict__ pcs2,
    float* __restrict__ cpart, unsigned* __restrict__ counter)
{
    __shared__ uint4 afrag[2048];   // 32 tiles * 2 K-halves * 32 rows = 32 KB

    const int bid = blockIdx.x;
    const int dir = bid >> 9;
    const int b   = (bid >> 6) & 7;
    const int rq  = (bid >> 4) & 3;
    const int mg  = bid & 15;
    const int tid = threadIdx.x;

    if (bid == 0 && tid == 0) *counter = 0u;   // reset for red1 (each call)

    const float* bbase = (dir ? pcs2 : pcs1) + (size_t)b * NPTS * 3;
    const float* abase = (dir ? pcs1 : pcs2) + (size_t)b * NPTS * 3;

    const int w   = tid >> 6;
    const int l   = tid & 63;
    const int hf  = l >> 5;
    const int ln  = l & 31;
    const int mt0 = mg * 8 + w * 2;

    // ---- wave-fixed B-frags (2 m-tiles, built in registers) ----
    FragCast bq0, bq1;
    {
        const float* s0 = bbase + (size_t)(mt0 * 32 + ln) * 3;
        bq0.u = build_bfrag(s0[0], s0[1], s0[2], hf);
        const float* s1 = bbase + (size_t)((mt0 + 1) * 32 + ln) * 3;
        bq1.u = build_bfrag(s1[0], s1[1], s1[2], hf);
    }

    // ---- stage A-frags: quarter rq (1024 points), built on the fly ----
    {
        const float4* src = (const float4*)(abase + (size_t)rq * 3072);
        float4 f0 = src[3 * tid + 0];
        float4 f1 = src[3 * tid + 1];
        float4 f2 = src[3 * tid + 2];
        float xs[4] = {f0.x, f0.w, f1.z, f2.y};
        float ys[4] = {f0.y, f1.x, f1.w, f2.z};
        float zs[4] = {f0.z, f1.y, f2.x, f2.w};
        const int jt = tid >> 3;
        const int r0 = (tid & 7) * 4;
#pragma unroll
        for (int i = 0; i < 4; ++i) {
            uint4 a0, a1;
            build_afrag(xs[i], ys[i], zs[i], a0, a1);
            afrag[jt * 64 + r0 + i]      = a0;
            afrag[jt * 64 + 32 + r0 + i] = a1;
        }
    }
    __syncthreads();

    const f32x16 cz = {0.f,0.f,0.f,0.f,0.f,0.f,0.f,0.f,
                       0.f,0.f,0.f,0.f,0.f,0.f,0.f,0.f};

    // persistent per-slot accumulators (16 independent lanes of min each)
    float acc0[16], acc1[16];
#pragma unroll
    for (int i = 0; i < 16; ++i) { acc0[i] = 3.4e38f; acc1[i] = 3.4e38f; }

    // ---- hot loop: 32 x (1 ds_read_b128 + 2 MFMA + 32 INDEPENDENT v_min)
#pragma unroll 2
    for (int j = 0; j < 32; ++j) {
        FragCast aq;
        aq.u = afrag[j * 64 + hf * 32 + ln];
        f32x16 D0 = __builtin_amdgcn_mfma_f32_32x32x16_bf16(aq.v, bq0.v, cz, 0, 0, 0);
        f32x16 D1 = __builtin_amdgcn_mfma_f32_32x32x16_bf16(aq.v, bq1.v, cz, 0, 0, 0);
#pragma unroll
        for (int i = 0; i < 16; ++i) acc0[i] = fminf(acc0[i], D0[i]);
#pragma unroll
        for (int i = 0; i < 16; ++i) acc1[i] = fminf(acc1[i], D1[i]);
    }

    // ---- epilogue: 15-op tree per acc array (once), cross-half, store ----
    float r0, r1;
    {
        float m0 = fminf(acc0[0],  acc0[1]);
        float m1 = fminf(acc0[2],  acc0[3]);
        float m2 = fminf(acc0[4],  acc0[5]);
        float m3 = fminf(acc0[6],  acc0[7]);
        float m4 = fminf(acc0[8],  acc0[9]);
        float m5 = fminf(acc0[10], acc0[11]);
        float m6 = fminf(acc0[12], acc0[13]);
        float m7 = fminf(acc0[14], acc0[15]);
        r0 = fminf(fminf(fminf(m0, m1), fminf(m2, m3)),
                   fminf(fminf(m4, m5), fminf(m6, m7)));
    }
    {
        float m0 = fminf(acc1[0],  acc1[1]);
        float m1 = fminf(acc1[2],  acc1[3]);
        float m2 = fminf(acc1[4],  acc1[5]);
        float m3 = fminf(acc1[6],  acc1[7]);
        float m4 = fminf(acc1[8],  acc1[9]);
        float m5 = fminf(acc1[10], acc1[11]);
        float m6 = fminf(acc1[12], acc1[13]);
        float m7 = fminf(acc1[14], acc1[15]);
        r1 = fminf(fminf(fminf(m0, m1), fminf(m2, m3)),
                   fminf(fminf(m4, m5), fminf(m6, m7)));
    }
    r0 = fminf(r0, __shfl_xor(r0, 32, 64));
    r1 = fminf(r1, __shfl_xor(r1, 32, 64));

    const int   mt  = mt0 + hf;
    const float val = fmaxf(hf ? r1 : r0, 0.0f);   // clamp cancellation
    cpart[((((size_t)(dir * 8 + b) * 128 + mt) * 4 + rq) << 5) + ln] = val;
}

// ---------------- red1: 65536 col-mins -> scalar (last-block-done) --------
__global__ __launch_bounds__(256) void chamfer_red1(
    const float* __restrict__ cpart, float* __restrict__ bpart,
    unsigned* __restrict__ counter, float* __restrict__ out)
{
    __shared__ float ws4[4];
    __shared__ int islast;
    const int t  = threadIdx.x;
    const int tg = blockIdx.x * 256 + t;        // [0, 65536): (dir,b,mt,ln)
    const float* p = cpart + ((size_t)(tg >> 5) << 7) + (tg & 31);
    float m = fminf(fminf(p[0], p[32]), fminf(p[64], p[96]));  // min over rq
    float s = sqrtf(m);                          // clamped in main
#pragma unroll
    for (int off = 1; off < 64; off <<= 1) s += __shfl_xor(s, off, 64);
    if ((t & 63) == 0) ws4[t >> 6] = s;
    __syncthreads();
    if (t == 0) {
        bpart[blockIdx.x] = ws4[0] + ws4[1] + ws4[2] + ws4[3];
        __threadfence();
        islast = (atomicAdd(counter, 1u) == 255u);
    }
    __syncthreads();
    if (islast) {                                // whole block participates
        __threadfence();                         // acquire all bpart writes
        float v = bpart[t];                      // 256 threads, 256 partials
#pragma unroll
        for (int off = 1; off < 64; off <<= 1) v += __shfl_xor(v, off, 64);
        if ((t & 63) == 0) ws4[t >> 6] = v;
        __syncthreads();
        if (t == 0)
            out[0] = (ws4[0] + ws4[1] + ws4[2] + ws4[3]) * (1.0f / 65536.0f);
        // loss = 0.5*(sum1/32768 + sum2/32768) = (sum1+sum2)/65536
    }
}

// ---------------- fallback (proven R5 vector path, 4KB ws) ----------------
#define CPAIRS 1024
#define PA 16
#define RSTRIDE 68

__device__ __forceinline__ f32x2 pk_fma_lo(f32x2 c, f32x2 q, f32x2 acc) {
    f32x2 d;
    asm("v_pk_fma_f32 %0, %1, %2, %3 op_sel:[0,0,0] op_sel_hi:[0,1,1]"
        : "=v"(d) : "v"(c), "v"(q), "v"(acc));
    return d;
}
__device__ __forceinline__ f32x2 pk_fma_hi(f32x2 c, f32x2 q, f32x2 acc) {
    f32x2 d;
    asm("v_pk_fma_f32 %0, %1, %2, %3 op_sel:[1,0,0] op_sel_hi:[1,1,1]"
        : "=v"(d) : "v"(c), "v"(q), "v"(acc));
    return d;
}
__device__ __forceinline__ void vmin3(float& acc, float a, float b) {
    asm("v_min3_f32 %0, %1, %2, %3" : "=v"(acc) : "v"(acc), "v"(a), "v"(b));
}

__global__ __launch_bounds__(256, 4) void chamfer_vec(
    const float* __restrict__ pcs1, const float* __restrict__ pcs2,
    float* __restrict__ partials)
{
    __shared__ float4 lds[2 * CPAIRS];
    float4* bx = lds;
    float4* bz = lds + CPAIRS;

    const int bid = blockIdx.x;
    const int dir = bid >> 9;
    const int b   = (bid >> 6) & 7;
    const int ach = bid & 63;

    const float* A  = dir ? pcs2 : pcs1;
    const float* Bp = dir ? pcs1 : pcs2;
    const float* abase = A  + (size_t)b * NPTS * 3;
    const float* bbase = Bp + (size_t)b * NPTS * 3;

    const int tid = threadIdx.x;
    const int w   = tid >> 6;
    const int l   = tid & 63;

    const int apt = ach * 64 + w * PA;
    f32x2 cx[PA / 2], cy[PA / 2], cz2[PA / 2];
    float tmin[PA];
#pragma unroll
    for (int p2 = 0; p2 < PA / 2; ++p2) {
        const float* s = abase + (size_t)(apt + 2 * p2) * 3;
        cx[p2]  = (f32x2){-2.0f * s[0], -2.0f * s[3]};
        cy[p2]  = (f32x2){-2.0f * s[1], -2.0f * s[4]};
        cz2[p2] = (f32x2){-2.0f * s[2], -2.0f * s[5]};
        tmin[2 * p2] = 3.4e38f; tmin[2 * p2 + 1] = 3.4e38f;
    }

    for (int c = 0; c < 2; ++c) {
        if (c) __syncthreads();
#pragma unroll
        for (int i = 0; i < CPAIRS / 256; ++i) {
            int j  = i * 256 + tid;
            const float* s = bbase + (size_t)(c * CPAIRS + j) * 6;
            float x0 = s[0], y0 = s[1], z0 = s[2];
            float x1 = s[3], y1 = s[4], z1 = s[5];
            bx[j] = make_float4(x0, x1, y0, y1);
            bz[j] = make_float4(z0, z1,
                                fmaf(x0, x0, fmaf(y0, y0, z0 * z0)),
                                fmaf(x1, x1, fmaf(y1, y1, z1 * z1)));
        }
        __syncthreads();
#pragma unroll 4
        for (int t = 0; t < CPAIRS / 64; ++t) {
            float4 X = bx[t * 64 + l];
            float4 Z = bz[t * 64 + l];
            f32x2 qx = (f32x2){X.x, X.y};
            f32x2 qy = (f32x2){X.z, X.w};
            f32x2 qz = (f32x2){Z.x, Z.y};
            f32x2 qw = (f32x2){Z.z, Z.w};
#pragma unroll
            for (int p2 = 0; p2 < PA / 2; ++p2) {
                f32x2 d0 = pk_fma_lo(cz2[p2], qz, qw);
                d0 = pk_fma_lo(cy[p2], qy, d0);
                d0 = pk_fma_lo(cx[p2], qx, d0);
                vmin3(tmin[2 * p2], d0.x, d0.y);
                f32x2 d1 = pk_fma_hi(cz2[p2], qz, qw);
                d1 = pk_fma_hi(cy[p2], qy, d1);
                d1 = pk_fma_hi(cx[p2], qx, d1);
                vmin3(tmin[2 * p2 + 1], d1.x, d1.y);
            }
        }
    }

    __syncthreads();
    float* lds2 = (float*)lds;
#pragma unroll
    for (int p = 0; p < PA; ++p)
        lds2[(w * PA + p) * RSTRIDE + l] = tmin[p];
    __syncthreads();

    if (tid < 64) {
        const int g = tid;
        float m = 3.4e38f;
        const float4* row = (const float4*)&lds2[g * RSTRIDE];
#pragma unroll
        for (int i = 0; i < 16; ++i) {
            float4 v = row[i];
            m = fminf(fminf(m, fminf(v.x, v.y)), fminf(v.z, v.w));
        }
        const int ap = ach * 64 + g;
        float x = abase[ap * 3 + 0], y = abase[ap * 3 + 1], z = abase[ap * 3 + 2];
        float s = sqrtf(fmaxf(fmaf(x, x, fmaf(y, y, z * z)) + m, 0.0f));
#pragma unroll
        for (int off = 1; off < 64; off <<= 1) s += __shfl_xor(s, off, 64);
        if (g == 0) partials[bid] = s;
    }
}

__global__ __launch_bounds__(256) void chamfer_final(
    const float* __restrict__ partials, int n, float scale,
    float* __restrict__ out)
{
    __shared__ float ws4[4];
    const int t = threadIdx.x;
    float v = 0.0f;
    for (int i = t; i < n; i += 256) v += partials[i];
#pragma unroll
    for (int off = 1; off < 64; off <<= 1) v += __shfl_xor(v, off, 64);
    if ((t & 63) == 0) ws4[t >> 6] = v;
    __syncthreads();
    if (t == 0)
        out[0] = (ws4[0] + ws4[1] + ws4[2] + ws4[3]) * scale;
}

extern "C" void kernel_launch(void* const* d_in, const int* in_sizes, int n_in,
                              void* d_out, int out_size, void* d_ws, size_t ws_size,
                              hipStream_t stream) {
    const float* pcs1 = (const float*)d_in[0];
    const float* pcs2 = (const float*)d_in[1];
    float* out = (float*)d_out;

    const size_t MB = 1048576;
    const size_t need = MB + 4096;

    if (ws_size >= need) {
        char* w = (char*)d_ws;
        float*    cpart   = (float*)(w);
        float*    bpart   = (float*)(w + MB);
        unsigned* counter = (unsigned*)(w + MB + 1024);

        chamfer_fused<<<dim3(1024), dim3(256), 0, stream>>>(
            pcs1, pcs2, cpart, counter);
        chamfer_red1 <<<dim3(256),  dim3(256), 0, stream>>>(
            cpart, bpart, counter, out);
    } else {
        float* partials = (float*)d_ws;
        chamfer_vec  <<<dim3(1024), dim3(256), 0, stream>>>(pcs1, pcs2, partials);
        chamfer_final<<<dim3(1),    dim3(256), 0, stream>>>(
            partials, 1024, 1.0f / 65536.0f, out);
    }
}